// Round 1
// baseline (5178.873 us; speedup 1.0000x reference)
//
#include <hip/hip_runtime.h>
#include <hip/hip_bf16.h>

#define SEQ 2048
#define NB  64
#define NIN 128
#define NH  256
// A-term layout: [t][group][gate][wave][ntile][lane][reg] bf16
// per (t,group): 3*8*2*64*4 = 12288 elems = 24 KB
#define AT_PER_TG 12288

typedef __bf16 bf16x8 __attribute__((ext_vector_type(8)));
typedef __bf16 bf16x4 __attribute__((ext_vector_type(4)));
typedef float  f32x4  __attribute__((ext_vector_type(4)));

__device__ __forceinline__ float fast_sigmoid(float x) {
    float e = __builtin_amdgcn_exp2f(-1.4426950408889634f * x);
    return __builtin_amdgcn_rcpf(1.0f + e);
}
__device__ __forceinline__ float fast_tanh(float x) {
    float e = __builtin_amdgcn_exp2f(2.8853900817779268f * x);
    return 1.0f - 2.0f * __builtin_amdgcn_rcpf(1.0f + e);
}

// ---------- phase 1: A-terms = x @ Wg_x^T  (frag-ordered bf16) -------------
// grid: SEQ*3 blocks (t, gate), 256 threads (4 waves = 4 M-tiles of 16 batches)
__global__ __launch_bounds__(256) void gru_pre(
        const float* __restrict__ x, const float* __restrict__ Wz,
        const float* __restrict__ Wr, const float* __restrict__ Wi,
        __bf16* __restrict__ At) {
    __shared__ __align__(16) __bf16 wlds[256][136];   // gate's x-part weights
    __shared__ __align__(16) __bf16 xlds[64][136];    // x[t]
    const int bid = blockIdx.x;
    const int t = bid / 3, gate = bid - t * 3;
    const float* W = (gate == 0) ? Wz : ((gate == 1) ? Wr : Wi);
    // x sits in cols [0,128) of Wz/Wr, cols [256,384) of Wi (hidden-first!)
    const int xoff = (gate == 2) ? NH : 0;
    const int tid = threadIdx.x;
    #pragma unroll
    for (int j = 0; j < 32; ++j) {
        int flat = j * 1024 + tid * 4;
        int row = flat >> 7, col = flat & 127;
        const float4 v = *(const float4*)(W + (size_t)row * 384 + xoff + col);
        wlds[row][col+0] = (__bf16)v.x; wlds[row][col+1] = (__bf16)v.y;
        wlds[row][col+2] = (__bf16)v.z; wlds[row][col+3] = (__bf16)v.w;
    }
    const float* xt = x + (size_t)t * (NB * NIN);
    #pragma unroll
    for (int j = 0; j < 8; ++j) {
        int flat = j * 1024 + tid * 4;
        int row = flat >> 7, col = flat & 127;
        const float4 v = *(const float4*)(xt + row * NIN + col);
        xlds[row][col+0] = (__bf16)v.x; xlds[row][col+1] = (__bf16)v.y;
        xlds[row][col+2] = (__bf16)v.z; xlds[row][col+3] = (__bf16)v.w;
    }
    __syncthreads();
    const int wv = tid >> 6, l = tid & 63;
    const int lrow = l & 15, lk = (l >> 4) * 8;
    bf16x8 a[4];
    #pragma unroll
    for (int kt = 0; kt < 4; ++kt)
        a[kt] = *(const bf16x8*)&xlds[wv * 16 + lrow][kt * 32 + lk];
    #pragma unroll
    for (int j = 0; j < 16; ++j) {
        f32x4 acc = {0.f, 0.f, 0.f, 0.f};
        #pragma unroll
        for (int kt = 0; kt < 4; ++kt) {
            bf16x8 b = *(const bf16x8*)&wlds[j * 16 + lrow][kt * 32 + lk];
            acc = __builtin_amdgcn_mfma_f32_16x16x32_bf16(a[kt], b, acc, 0, 0, 0);
        }
        size_t off = (size_t)(t * 4 + wv) * AT_PER_TG
                   + (size_t)(((gate * 8 + (j >> 1)) * 2 + (j & 1)) * 256 + l * 4);
        bf16x4 o;
        o[0]=(__bf16)acc[0]; o[1]=(__bf16)acc[1]; o[2]=(__bf16)acc[2]; o[3]=(__bf16)acc[3];
        *(bf16x4*)(At + off) = o;
    }
}

// ---------- phase 2: recurrence. 4 blocks x 512 thr; 16 batches/CU ----------
// All recurrent weights live persistently in VGPRs as MFMA B-fragments.
__global__ __launch_bounds__(512, 2) void gru_rec(
        const float* __restrict__ h0, const float* __restrict__ Wz,
        const float* __restrict__ Wr, const float* __restrict__ Wi,
        const __bf16* __restrict__ At, float* __restrict__ out) {
    __shared__ __align__(16) __bf16 hB[16][264];      // h (bf16) for A-operand
    __shared__ __align__(16) __bf16 rhB[16][264];     // r*h
    __shared__ __align__(16) __bf16 ring[4][AT_PER_TG]; // A-term prefetch ring
    const int g = blockIdx.x;                          // batch group
    const int tid = threadIdx.x;
    const int wv = tid >> 6, l = tid & 63;
    const int lrow = l & 15;       // A row / B col / C col
    const int lk = (l >> 4) * 8;   // k-slice base
    const int crow = (l >> 4) * 4; // C row base
    const int hid0 = wv * 32 + lrow;

    // ---- load recurrent weights into registers (once) ----
    bf16x8 Wf[3][2][8];  // [gate][ntile][ktile]
    {
        const float* Wp[3] = {Wz, Wr, Wi};
        #pragma unroll
        for (int gg = 0; gg < 3; ++gg) {
            const int koff = (gg == 2) ? 0 : 128;   // h-part columns
            #pragma unroll
            for (int nt = 0; nt < 2; ++nt) {
                const float* row = Wp[gg] + (size_t)(hid0 + nt * 16) * 384 + koff;
                #pragma unroll
                for (int kt = 0; kt < 8; ++kt) {
                    const float4 v0 = *(const float4*)(row + kt * 32 + lk);
                    const float4 v1 = *(const float4*)(row + kt * 32 + lk + 4);
                    bf16x8 f;
                    f[0]=(__bf16)v0.x; f[1]=(__bf16)v0.y; f[2]=(__bf16)v0.z; f[3]=(__bf16)v0.w;
                    f[4]=(__bf16)v1.x; f[5]=(__bf16)v1.y; f[6]=(__bf16)v1.z; f[7]=(__bf16)v1.w;
                    Wf[gg][nt][kt] = f;
                }
            }
        }
    }
    // ---- init h (f32 regs, C-frag coords) + hB ----
    float h[2][4];
    #pragma unroll
    for (int nt = 0; nt < 2; ++nt)
        #pragma unroll
        for (int q = 0; q < 4; ++q) {
            float v = h0[(size_t)(g * 16 + crow + q) * NH + hid0 + nt * 16];
            h[nt][q] = v;
            hB[crow + q][hid0 + nt * 16] = (__bf16)v;
        }
    // ---- prologue: prefetch ring slots 0..2 (wave prefetches only what it reads) ----
    #pragma unroll
    for (int s = 0; s < 3; ++s) {
        #pragma unroll
        for (int gg = 0; gg < 3; ++gg) {
            const int chunk = gg * 8 + wv;
            const __bf16* src = At + (size_t)(s * 4 + g) * AT_PER_TG + chunk * 512 + l * 8;
            __builtin_amdgcn_global_load_lds(
                (const __attribute__((address_space(1))) void*)src,
                (__attribute__((address_space(3))) void*)&ring[s][chunk * 512], 16, 0, 0);
        }
    }
    asm volatile("s_waitcnt lgkmcnt(0)" ::: "memory");
    __builtin_amdgcn_s_barrier();

    float* outp = out + (size_t)(g * 16 + crow) * NH + hid0;
    #pragma clang loop unroll(disable)
    for (int t = 0; t < SEQ; ++t) {
        const int slot = t & 3;
        // issue prefetch for t+3 (clamped at tail; redundant loads are harmless)
        {
            const int tp = (t + 3 < SEQ) ? (t + 3) : (SEQ - 1);
            const int sp = (t + 3) & 3;
            #pragma unroll
            for (int gg = 0; gg < 3; ++gg) {
                const int chunk = gg * 8 + wv;
                const __bf16* src = At + (size_t)(tp * 4 + g) * AT_PER_TG + chunk * 512 + l * 8;
                __builtin_amdgcn_global_load_lds(
                    (const __attribute__((address_space(1))) void*)src,
                    (__attribute__((address_space(3))) void*)&ring[sp][chunk * 512], 16, 0, 0);
            }
        }
        // per-wave vm ops per step: 3 loads + 8 stores -> slot-t ready at 33
        if (t < 3) { asm volatile("s_waitcnt vmcnt(9)" ::: "memory"); }
        else       { asm volatile("s_waitcnt vmcnt(33)" ::: "memory"); }

        const __bf16* rb = &ring[slot][0];
        // ---- z,r gemms; acc initialized from precomputed x-terms ----
        f32x4 az[2], ar[2];
        #pragma unroll
        for (int nt = 0; nt < 2; ++nt) {
            bf16x4 tz = *(const bf16x4*)(rb + ((0  + wv) * 2 + nt) * 256 + l * 4);
            bf16x4 tr = *(const bf16x4*)(rb + ((8  + wv) * 2 + nt) * 256 + l * 4);
            az[nt][0]=(float)tz[0]; az[nt][1]=(float)tz[1]; az[nt][2]=(float)tz[2]; az[nt][3]=(float)tz[3];
            ar[nt][0]=(float)tr[0]; ar[nt][1]=(float)tr[1]; ar[nt][2]=(float)tr[2]; ar[nt][3]=(float)tr[3];
        }
        #pragma unroll
        for (int kt = 0; kt < 8; ++kt) {
            bf16x8 ha = *(const bf16x8*)&hB[lrow][kt * 32 + lk];
            az[0] = __builtin_amdgcn_mfma_f32_16x16x32_bf16(ha, Wf[0][0][kt], az[0], 0,0,0);
            az[1] = __builtin_amdgcn_mfma_f32_16x16x32_bf16(ha, Wf[0][1][kt], az[1], 0,0,0);
            ar[0] = __builtin_amdgcn_mfma_f32_16x16x32_bf16(ha, Wf[1][0][kt], ar[0], 0,0,0);
            ar[1] = __builtin_amdgcn_mfma_f32_16x16x32_bf16(ha, Wf[1][1][kt], ar[1], 0,0,0);
        }
        // ---- r = sigmoid, write r*h; z = sigmoid (overlaps barrier wait) ----
        float z[2][4];
        #pragma unroll
        for (int nt = 0; nt < 2; ++nt)
            #pragma unroll
            for (int q = 0; q < 4; ++q) {
                float r = fast_sigmoid(ar[nt][q]);
                rhB[crow + q][hid0 + nt * 16] = (__bf16)(r * h[nt][q]);
                z[nt][q] = fast_sigmoid(az[nt][q]);
            }
        asm volatile("s_waitcnt lgkmcnt(0)" ::: "memory");
        __builtin_amdgcn_s_barrier();
        // ---- inter gemm on (r*h) ----
        f32x4 ai[2];
        #pragma unroll
        for (int nt = 0; nt < 2; ++nt) {
            bf16x4 ti = *(const bf16x4*)(rb + ((16 + wv) * 2 + nt) * 256 + l * 4);
            ai[nt][0]=(float)ti[0]; ai[nt][1]=(float)ti[1]; ai[nt][2]=(float)ti[2]; ai[nt][3]=(float)ti[3];
        }
        #pragma unroll
        for (int kt = 0; kt < 8; ++kt) {
            bf16x8 ra = *(const bf16x8*)&rhB[lrow][kt * 32 + lk];
            ai[0] = __builtin_amdgcn_mfma_f32_16x16x32_bf16(ra, Wf[2][0][kt], ai[0], 0,0,0);
            ai[1] = __builtin_amdgcn_mfma_f32_16x16x32_bf16(ra, Wf[2][1][kt], ai[1], 0,0,0);
        }
        // ---- tanh, blend, store out + hB for next step ----
        float* ot = outp + (size_t)t * (NB * NH);
        #pragma unroll
        for (int nt = 0; nt < 2; ++nt)
            #pragma unroll
            for (int q = 0; q < 4; ++q) {
                float it = fast_tanh(ai[nt][q]);
                float hn = h[nt][q] + z[nt][q] * (it - h[nt][q]);
                h[nt][q] = hn;
                ot[(size_t)q * NH + nt * 16] = hn;
                hB[crow + q][hid0 + nt * 16] = (__bf16)hn;
            }
        asm volatile("s_waitcnt lgkmcnt(0)" ::: "memory");
        __builtin_amdgcn_s_barrier();
    }
}

extern "C" void kernel_launch(void* const* d_in, const int* in_sizes, int n_in,
                              void* d_out, int out_size, void* d_ws, size_t ws_size,
                              hipStream_t stream) {
    const float* x  = (const float*)d_in[0];
    const float* h0 = (const float*)d_in[1];
    const float* Wz = (const float*)d_in[2];
    const float* Wr = (const float*)d_in[3];
    const float* Wi = (const float*)d_in[4];
    __bf16* At = (__bf16*)d_ws;   // needs SEQ*4*AT_PER_TG*2 = ~192 MiB
    (void)in_sizes; (void)n_in; (void)out_size; (void)ws_size;

    gru_pre<<<dim3(SEQ * 3), dim3(256), 0, stream>>>(x, Wz, Wr, Wi, At);
    gru_rec<<<dim3(4), dim3(512), 0, stream>>>(h0, Wz, Wr, Wi, At, (float*)d_out);
}